// Round 20
// baseline (272.540 us; speedup 1.0000x reference)
//
#include <hip/hip_runtime.h>
#include <hip/hip_bf16.h>
#include <math.h>

#define HH 48
#define WW 48
#define HW 2304
#define BB 4
#define CC 256

typedef __hip_bfloat16 bf16;
typedef __attribute__((ext_vector_type(8))) short s8v;
typedef __attribute__((ext_vector_type(4))) float f4v;

__device__ inline float bf2f(short u) {
  unsigned v = ((unsigned)(unsigned short)u) << 16;
  return __builtin_bit_cast(float, v);
}

// ---------------- prep: z<4 -> fmap2 transpose; z>=4 -> fmap1 transpose + srcT/qb ----
__global__ __launch_bounds__(256) void prep_k(const float* __restrict__ fmap1,
                                              const float* __restrict__ fmap2,
                                              float* __restrict__ srcT,
                                              bf16* __restrict__ f1t,
                                              bf16* __restrict__ qb,
                                              bf16* __restrict__ f2t) {
  __shared__ float t[64][65];
  int z = blockIdx.z;
  int p0 = blockIdx.x * 64, c0 = blockIdx.y * 64;
  int b = z & 3;
  const float* src = (z < 4) ? fmap2 : fmap1;
  const float* inb = src + ((size_t)b * CC + c0) * HW + p0;
#pragma unroll
  for (int i = 0; i < 16; ++i) {
    int idx = threadIdx.x + i * 256;
    int c = idx >> 6, p = idx & 63;
    t[c][p] = inb[(size_t)c * HW + p];
  }
  __syncthreads();
  if (z < 4) {
    bf16* ob = f2t + ((size_t)b * HW + p0) * 256 + c0;
#pragma unroll
    for (int i = 0; i < 16; ++i) {
      int idx = threadIdx.x + i * 256;
      int p = idx >> 6, c = idx & 63;
      ob[(size_t)p * 256 + c] = (bf16)t[c][p];
    }
  } else {
    const float TWO_PI = 6.283185307179586f;
#pragma unroll
    for (int i = 0; i < 16; ++i) {
      int idx = threadIdx.x + i * 256;
      int pl = idx >> 6, cl = idx & 63;
      int c = c0 + cl;
      int p = p0 + pl;
      int y = p / WW, x = p % WW;
      float s = t[cl][pl];
      int axis = c >> 7;
      int cc = c & 127;
      int mm = cc >> 1;
      float coord = (axis ? ((float)x + 0.5f) : ((float)y + 0.5f)) * (TWO_PI / (48.f + 1e-6f));
      float tp = exp2f((float)mm * (13.287712379549449f / 64.f));
      float a = coord / tp;
      float pv = (cc & 1) ? cosf(a) : sinf(a);
      size_t o = ((size_t)b * HW + p) * 256 + c;
      srcT[o] = s;
      f1t[o] = (bf16)s;
      qb[o] = (bf16)(s + pv);
    }
  }
}

// ---------------- FUSED corr+lookup: 1024-thr blocks, 4 queries x 4 K-split waves ----
__global__ __launch_bounds__(1024) void fused_corr_k(const bf16* __restrict__ f1t,
                                                     const bf16* __restrict__ f2t,
                                                     const float* __restrict__ flow,
                                                     bf16* __restrict__ cf) {
  __shared__ float Dp[4][4][112];
  __shared__ float Ds[4][112];
  __shared__ float wxs[4], wys[4];
  int cb = blockIdx.x;
  int iq = (cb & 7) * 288 + (cb >> 3);  // bijective XCD swizzle over 2304 blocks
  int tid = threadIdx.x;
  int wave = tid >> 6, lane = tid & 63;
  int qi = wave >> 2, kw = wave & 3;
  int q = iq * 4 + qi;
  int b = q / HW, p = q - b * HW;
  int y = p / WW, x = p - y * WW;
  float fx = flow[((size_t)b * 2 + 0) * HW + p];
  float fy = flow[((size_t)b * 2 + 1) * HW + p];
  float sx = (float)x + fx, sy = (float)y + fy;
  float fx0 = floorf(sx), fy0 = floorf(sy);
  int ix0 = (int)fx0, iy0 = (int)fy0;
  float wx = sx - fx0, wy = sy - fy0;
  if (kw == 0 && lane == 0) {
    wxs[qi] = wx;
    wys[qi] = wy;
  }
  int fl = lane & 15, fk8 = lane >> 4;
  const bf16* f1q = f1t + (size_t)q * 256 + kw * 64;
  s8v bf0 = *(const s8v*)(f1q + fk8 * 8);
  s8v bf1v = *(const s8v*)(f1q + 32 + fk8 * 8);
  const bf16* rowp[7];
#pragma unroll
  for (int g = 0; g < 7; ++g) {
    int w = g * 16 + fl;
    int jy = w / 10, jx = w - jy * 10;
    int ky = iy0 - 4 + jy, kx = ix0 - 4 + jx;
    bool valid = (w < 100) && ((unsigned)kx < (unsigned)WW) && ((unsigned)ky < (unsigned)HH);
    rowp[g] = valid ? (f2t + ((size_t)b * HW + ky * WW + kx) * 256 + kw * 64) : nullptr;
  }
  s8v a0[7], a1[7];
#pragma unroll
  for (int g = 0; g < 7; ++g) {
    s8v z = {0, 0, 0, 0, 0, 0, 0, 0};
    a0[g] = rowp[g] ? *(const s8v*)(rowp[g] + fk8 * 8) : z;
  }
#pragma unroll
  for (int g = 0; g < 7; ++g) {
    s8v z = {0, 0, 0, 0, 0, 0, 0, 0};
    a1[g] = rowp[g] ? *(const s8v*)(rowp[g] + 32 + fk8 * 8) : z;
  }
  f4v acc[7] = {};
#pragma unroll
  for (int g = 0; g < 7; ++g)
    acc[g] = __builtin_amdgcn_mfma_f32_16x16x32_bf16(a0[g], bf0, acc[g], 0, 0, 0);
#pragma unroll
  for (int g = 0; g < 7; ++g)
    acc[g] = __builtin_amdgcn_mfma_f32_16x16x32_bf16(a1[g], bf1v, acc[g], 0, 0, 0);
  if (fl == 0) {
#pragma unroll
    for (int g = 0; g < 7; ++g)
#pragma unroll
      for (int r = 0; r < 4; ++r)
        Dp[qi][kw][g * 16 + fk8 * 4 + r] = acc[g][r];
  }
  __syncthreads();
  if (tid < 448) {
    int qj = tid / 112, t = tid - qj * 112;
    Ds[qj][t] = (Dp[qj][0][t] + Dp[qj][1][t] + Dp[qj][2][t] + Dp[qj][3][t]) * 0.0625f;
  }
  __syncthreads();
  if (tid < 384) {
    int qj = tid / 96, t = tid - qj * 96;
    float wxq = wxs[qj], wyq = wys[qj];
    float w00 = (1.f - wxq) * (1.f - wyq), w10 = wxq * (1.f - wyq);
    float w01 = (1.f - wxq) * wyq, w11 = wxq * wyq;
    float v = 0.f;
    if (t < 81) {
      int jx = t / 9, jy = t - jx * 9;  // px offset uses t/9, py uses t%9 (RAFT quirk)
      const float* D = Ds[qj];
      v = w00 * D[jy * 10 + jx] + w10 * D[jy * 10 + jx + 1] +
          w01 * D[(jy + 1) * 10 + jx] + w11 * D[(jy + 1) * 10 + jx + 1];
    }
    cf[(size_t)(iq * 4 + qj) * 96 + t] = (bf16)v;
  }
}

// ---------------- fused weight conversion: 12 segments (KS2==0 => conv7 repack) ----
struct WtSegs {
  const float* src[12];
  unsigned dstOff[12];
  int Cout[12], Cin[12], KP[12], KS2[12];
  unsigned cum[13];
};

__global__ __launch_bounds__(256) void wt_all_k(WtSegs s, bf16* __restrict__ base) {
  unsigned idx = blockIdx.x * 256 + threadIdx.x;
  if (idx >= s.cum[12]) return;
  int seg = 0;
#pragma unroll
  for (int i = 1; i < 12; ++i)
    if (idx >= s.cum[i]) seg = i;
  unsigned r = idx - s.cum[seg];
  int KP = s.KP[seg], Cout = s.Cout[seg], Cin = s.Cin[seg], KS2 = s.KS2[seg];
  int c = r % KP;
  int o = (r / KP) % Cout;
  int t = r / (KP * Cout);
  float v;
  if (KS2 == 0) {
    int cc = c >> 6, tt = c & 63;
    v = (tt < 49) ? s.src[seg][((size_t)o * 2 + cc) * 49 + tt] : 0.f;
  } else {
    v = (c < Cin) ? s.src[seg][((size_t)o * Cin + c) * KS2 + t] : 0.f;
  }
  base[s.dstOff[seg] + r] = (bf16)v;
}

// ---------------- im2col for 7x7 pad3 conv on flow: col7[n][128] bf16 ----
__global__ __launch_bounds__(256) void im2col7_k(const float* __restrict__ flow,
                                                 bf16* __restrict__ col7) {
  int g = blockIdx.x * 256 + threadIdx.x;
  int kp = g & 127;
  int n = g >> 7;
  int b = n / HW;
  int p = n % HW;
  int y = p / WW, x = p % WW;
  int cc = kp >> 6, tt = kp & 63;
  float v = 0.f;
  if (tt < 49) {
    int ky = tt / 7, kx = tt % 7;
    int yy = y + ky - 3, xx = x + kx - 3;
    if ((unsigned)yy < (unsigned)HH && (unsigned)xx < (unsigned)WW)
      v = flow[((size_t)b * 2 + cc) * HW + yy * WW + xx];
  }
  col7[g] = (bf16)v;
}

// ---------------- grouped GEMM: 2-deep reg prefetch + LDS dbuf (S always even) ----
struct GSegs {
  const bf16* in[4];
  const bf16* wt[4];
  const float* bias[4];
  const float* bias2[4];
  float* outf[4];
  bf16* outb[4];
  int split[4], O[4], KP[4], taps[4], OStride[4], OOff[4], relu[4], nTn[4];
  int blkStart[4];
  int nseg;
};

__global__ __launch_bounds__(256) void gemm_group_k(GSegs s) {
  int blk = blockIdx.x;
  int seg = 0;
#pragma unroll
  for (int i = 1; i < 4; ++i)
    if (i < s.nseg && blk >= s.blkStart[i]) seg = i;
  int rel = blk - s.blkStart[seg];
  int nTn = s.nTn[seg];
  int bm = rel / nTn, bn = rel % nTn;
  int m0 = bm * 128, n0 = bn * 64;
  int KP = s.KP[seg], O = s.O[seg], taps = s.taps[seg];
  const bf16* in = s.in[seg];
  const bf16* wt = s.wt[seg];

  __shared__ short As[2][128][64];
  __shared__ short Bs[2][64][64];
  int tid = threadIdx.x;
  int arl = tid >> 1, asl = (tid & 1) * 4;
  int brl = tid >> 2, bsl = (tid & 3) * 2;
  int wave = tid >> 6, lane = tid & 63;
  int wm = (wave >> 1) * 64, wn = (wave & 1) * 32;
  int fl = lane & 15, fk8 = lane >> 4;
  f4v acc[4][2] = {};
  int m = m0 + arl;
  int b = m / HW;
  int p = m - b * HW;
  int y = p / WW, x = p - y * WW;
  int wo = n0 + brl;
  bool wvalid = wo < O;
  int wo_c = wvalid ? wo : 0;

  int nc0 = (KP + 63) >> 6;
  int S = taps * nc0;  // even for all launched segments
  uint4 apA[4], bpA[2], apB[4], bpB[2];

  auto load_stage = [&](int st, uint4* ap, uint4* bp) {
    int t = st / nc0;
    int c0 = (st - t * nc0) * 64;
    int yy = y, xx = x;
    bool valid = true;
    if (taps == 9) {
      int ky = t / 3, kx = t - ky * 3;
      yy = y + ky - 1;
      xx = x + kx - 1;
      valid = ((unsigned)yy < (unsigned)HH) & ((unsigned)xx < (unsigned)WW);
    }
    const bf16* arow = in + ((size_t)b * HW + yy * WW + xx) * KP;
    const bf16* wrow = wt + ((size_t)t * O + wo_c) * KP;
#pragma unroll
    for (int qq = 0; qq < 4; ++qq) {
      int col = c0 + (asl + qq) * 8;
      uint4 v = {0u, 0u, 0u, 0u};
      if (valid && col < KP) v = *(const uint4*)(arow + col);
      ap[qq] = v;
    }
#pragma unroll
    for (int qq = 0; qq < 2; ++qq) {
      int col = c0 + (bsl + qq) * 8;
      uint4 v = {0u, 0u, 0u, 0u};
      if (wvalid && col < KP) v = *(const uint4*)(wrow + col);
      bp[qq] = v;
    }
  };
  auto write_lds = [&](int cur, const uint4* ap, const uint4* bp) {
#pragma unroll
    for (int qq = 0; qq < 4; ++qq) {
      int sr = asl + qq;
      *(uint4*)&As[cur][arl][((sr ^ (arl & 7))) * 8] = ap[qq];
    }
#pragma unroll
    for (int qq = 0; qq < 2; ++qq) {
      int sr = bsl + qq;
      *(uint4*)&Bs[cur][brl][((sr ^ (brl & 7))) * 8] = bp[qq];
    }
  };
  auto compute = [&](int cur) {
#pragma unroll
    for (int cc = 0; cc < 2; ++cc) {
      s8v af[4], bfr[2];
#pragma unroll
      for (int i = 0; i < 4; ++i) {
        int ar = wm + i * 16 + fl;
        af[i] = *(const s8v*)&As[cur][ar][(((cc * 4 + fk8) ^ (ar & 7))) * 8];
      }
#pragma unroll
      for (int j = 0; j < 2; ++j) {
        int br = wn + j * 16 + fl;
        bfr[j] = *(const s8v*)&Bs[cur][br][(((cc * 4 + fk8) ^ (br & 7))) * 8];
      }
#pragma unroll
      for (int i = 0; i < 4; ++i)
#pragma unroll
        for (int j = 0; j < 2; ++j)
          acc[i][j] = __builtin_amdgcn_mfma_f32_16x16x32_bf16(af[i], bfr[j], acc[i][j], 0, 0, 0);
    }
  };

  load_stage(0, apA, bpA);
  if (S > 1) load_stage(1, apB, bpB);
  for (int st = 0; st < S; st += 2) {
    write_lds(0, apA, bpA);
    if (st + 2 < S) load_stage(st + 2, apA, bpA);
    __syncthreads();
    compute(0);
    write_lds(1, apB, bpB);
    if (st + 3 < S) load_stage(st + 3, apB, bpB);
    __syncthreads();
    compute(1);
  }

  int OStride = s.OStride[seg], OOff = s.OOff[seg], relu = s.relu[seg], split = s.split[seg];
  const float* bias = s.bias[seg];
  const float* bias2 = s.bias2[seg];
  float* outf = s.outf[seg];
  bf16* outb = s.outb[seg];
#pragma unroll
  for (int j = 0; j < 2; ++j) {
    int o = n0 + wn + j * 16 + fl;
    if (o < O) {
      float bsv = (bias2 != nullptr && o >= split) ? bias2[o - split] : bias[o];
#pragma unroll
      for (int i = 0; i < 4; ++i)
#pragma unroll
        for (int r = 0; r < 4; ++r) {
          int mm = m0 + wm + i * 16 + fk8 * 4 + r;
          float v = acc[i][j][r] + bsv;
          if (relu) v = fmaxf(v, 0.f);
          if (outb) outb[(size_t)mm * OStride + OOff + o] = (bf16)v;
          else outf[(size_t)mm * OStride + OOff + o] = v;
        }
    }
  }
}

// ---------------- final 3x3 conv 256->2, wave-per-pixel, LDS weights ----------------
__global__ __launch_bounds__(256) void convfh2_k(const bf16* __restrict__ fh1,
                                                 const float* __restrict__ w,
                                                 const float* __restrict__ bias,
                                                 float* __restrict__ out) {
  __shared__ float wl[4608];
  int tid = threadIdx.x;
#pragma unroll
  for (int i = tid; i < 4608; i += 256) {
    int o2 = i & 1;
    int t = (i >> 1) % 9;
    int c = i / 18;
    wl[i] = w[((size_t)o2 * 256 + c) * 9 + t];
  }
  __syncthreads();
  int wave = tid >> 6, lane = tid & 63;
  int pix = blockIdx.x * 4 + wave;
  int b = pix / HW;
  int q = pix % HW;
  int y = q / WW, x = q % WW;
  int c0 = lane * 4;
  float a0 = 0.f, a1 = 0.f;
#pragma unroll
  for (int ky = 0; ky < 3; ++ky) {
    int yy = y + ky - 1;
    if ((unsigned)yy >= (unsigned)HH) continue;
#pragma unroll
    for (int kx = 0; kx < 3; ++kx) {
      int xx = x + kx - 1;
      if ((unsigned)xx >= (unsigned)WW) continue;
      int t = ky * 3 + kx;
      const bf16* row = fh1 + ((size_t)b * HW + yy * WW + xx) * 256 + c0;
      ushort4 v = *(const ushort4*)row;
      unsigned short vv[4] = {v.x, v.y, v.z, v.w};
#pragma unroll
      for (int j = 0; j < 4; ++j) {
        float fv = bf2f((short)vv[j]);
        float2 wp = *(const float2*)&wl[((c0 + j) * 9 + t) * 2];
        a0 += fv * wp.x;
        a1 += fv * wp.y;
      }
    }
  }
#pragma unroll
  for (int offl = 32; offl > 0; offl >>= 1) {
    a0 += __shfl_xor(a0, offl);
    a1 += __shfl_xor(a1, offl);
  }
  if (lane == 0) {
    out[(size_t)b * 2 * HW + q] = a0 + bias[0];
    out[((size_t)b * 2 + 1) * HW + q] = a1 + bias[1];
  }
}

// ---------------- copy flow into mf cols 126,127 ----------------
__global__ void copy_flow_k(const float* __restrict__ flow, bf16* __restrict__ mf) {
  int g = blockIdx.x * 256 + threadIdx.x;
  int p = g % HW;
  int c = (g / HW) % 2;
  int b = g / (2 * HW);
  mf[((size_t)b * HW + p) * 128 + 126 + c] = (bf16)flow[g];
}

// ---------------- deformable sampling, 1024-thr blocks (4 queries), XCD swizzle ----
__global__ __launch_bounds__(1024) void deform_k(const bf16* __restrict__ val,
                                                 const float* __restrict__ oa,
                                                 bf16* __restrict__ attn) {
  int cb = blockIdx.x;
  int iq = (cb & 7) * 288 + (cb >> 3);  // bijective over 2304 blocks
  int tid = threadIdx.x;
  int d = tid & 31;
  int h = (tid >> 5) & 7;
  int qi = tid >> 8;
  int n = iq * 4 + qi;
  int b = n / HW;
  int p = n % HW;
  int y = p / WW, x = p % WW;
  const float* ap = oa + (size_t)n * 96 + 64 + h * 4;
  float l0 = ap[0], l1 = ap[1], l2 = ap[2], l3 = ap[3];
  float mx = fmaxf(fmaxf(l0, l1), fmaxf(l2, l3));
  float e0 = expf(l0 - mx), e1 = expf(l1 - mx), e2 = expf(l2 - mx), e3 = expf(l3 - mx);
  float inv = 1.f / (e0 + e1 + e2 + e3);
  float wts[4] = {e0 * inv, e1 * inv, e2 * inv, e3 * inv};
  const float* offp = oa + (size_t)n * 96 + h * 8;
  const bf16* vb = val + (size_t)b * HW * 256 + h * 32 + d;
  float acc = 0.f;
#pragma unroll
  for (int pt = 0; pt < 4; ++pt) {
    float ox = offp[pt * 2 + 0];
    float oy = offp[pt * 2 + 1];
    float w = wts[pt];
    float px = (float)x + ox, py = (float)y + oy;
    float x0f = floorf(px), y0f = floorf(py);
    int x0 = (int)x0f, y0 = (int)y0f;
    float wx = px - x0f, wy = py - y0f;
    float s = 0.f;
    if ((unsigned)x0 < WW && (unsigned)y0 < HH)
      s += (float)vb[(size_t)(y0 * WW + x0) * 256] * (1.f - wx) * (1.f - wy);
    if ((unsigned)(x0 + 1) < WW && (unsigned)y0 < HH)
      s += (float)vb[(size_t)(y0 * WW + x0 + 1) * 256] * wx * (1.f - wy);
    if ((unsigned)x0 < WW && (unsigned)(y0 + 1) < HH)
      s += (float)vb[(size_t)((y0 + 1) * WW + x0) * 256] * (1.f - wx) * wy;
    if ((unsigned)(x0 + 1) < WW && (unsigned)(y0 + 1) < HH)
      s += (float)vb[(size_t)((y0 + 1) * WW + x0 + 1) * 256] * wx * wy;
    acc += w * s;
  }
  attn[(size_t)n * 256 + h * 32 + d] = (bf16)acc;
}

// ---------------- fused residual add + LayerNorm over 256 (optional bf16 copy) ----
__global__ __launch_bounds__(256) void ln_add_k(const float* __restrict__ A,
                                                const float* __restrict__ Bv,
                                                const float* __restrict__ g,
                                                const float* __restrict__ be,
                                                float* __restrict__ out,
                                                bf16* __restrict__ outb) {
  int n = blockIdx.x;
  int c = threadIdx.x;
  float v = A[(size_t)n * 256 + c] + Bv[(size_t)n * 256 + c];
  float s1 = v, s2 = v * v;
#pragma unroll
  for (int o = 32; o > 0; o >>= 1) {
    s1 += __shfl_down(s1, o);
    s2 += __shfl_down(s2, o);
  }
  __shared__ float r1[4], r2[4], mv[2];
  int wid = c >> 6, lane = c & 63;
  if (lane == 0) {
    r1[wid] = s1;
    r2[wid] = s2;
  }
  __syncthreads();
  if (c == 0) {
    float a = r1[0] + r1[1] + r1[2] + r1[3];
    float q2 = r2[0] + r2[1] + r2[2] + r2[3];
    float mean = a * (1.f / 256.f);
    mv[0] = mean;
    mv[1] = q2 * (1.f / 256.f) - mean * mean;
  }
  __syncthreads();
  float mean = mv[0], var = mv[1];
  float r = (v - mean) * rsqrtf(var + 1e-5f) * g[c] + be[c];
  out[(size_t)n * 256 + c] = r;
  if (outb) outb[(size_t)n * 256 + c] = (bf16)r;
}

extern "C" void kernel_launch(void* const* d_in, const int* in_sizes, int n_in,
                              void* d_out, int out_size, void* d_ws, size_t ws_size,
                              hipStream_t stream) {
  const float* fmap1 = (const float*)d_in[0];
  const float* fmap2 = (const float*)d_in[1];
  const float* flow = (const float*)d_in[2];
  const float* wc1 = (const float*)d_in[3];
  const float* bc1 = (const float*)d_in[4];
  const float* wc2 = (const float*)d_in[5];
  const float* bc2 = (const float*)d_in[6];
  const float* wf1 = (const float*)d_in[7];
  const float* bf1 = (const float*)d_in[8];
  const float* wf2 = (const float*)d_in[9];
  const float* bf2 = (const float*)d_in[10];
  const float* wcf = (const float*)d_in[11];
  const float* bcf = (const float*)d_in[12];
  const float* wfh1 = (const float*)d_in[13];
  const float* bfh1 = (const float*)d_in[14];
  const float* wfh2 = (const float*)d_in[15];
  const float* bfh2 = (const float*)d_in[16];
  const float* w_off = (const float*)d_in[17];
  const float* b_off = (const float*)d_in[18];
  const float* w_aw = (const float*)d_in[19];
  const float* b_aw = (const float*)d_in[20];
  const float* w_val = (const float*)d_in[21];
  const float* b_val = (const float*)d_in[22];
  const float* w_out = (const float*)d_in[23];
  const float* b_out = (const float*)d_in[24];
  const float* ln1_g = (const float*)d_in[25];
  const float* ln1_b = (const float*)d_in[26];
  const float* w_ff1 = (const float*)d_in[27];
  const float* b_ff1 = (const float*)d_in[28];
  const float* w_ff2 = (const float*)d_in[29];
  const float* b_ff2 = (const float*)d_in[30];
  const float* ln2_g = (const float*)d_in[31];
  const float* ln2_b = (const float*)d_in[32];

  float* ws = (float*)d_ws;
  float* out_src = (float*)d_out;
  float* out_df = out_src + (size_t)BB * HW * CC;

  // ---- workspace layout (float offsets) ----
  const size_t F_WT = 0;
  const size_t F_F1T = 11700000;
  const size_t F_F2T = 12900000;
  const size_t F_QB = 14100000;
  const size_t F_SRCT = 15300000;
  const size_t F_CF = 17700000;
  const size_t F_COL7 = 18200000;
  const size_t F_COR1 = 18800000;
  const size_t F_FLO1 = 20000000;
  const size_t F_CAT = 20600000;
  const size_t F_MF = 21800000;
  const size_t F_FH1 = 22400000;
  const size_t F_OA = 23600000;
  const size_t F_VAL = 24500000;   // bf16 [n][256]
  const size_t F_ATTN = 26900000;
  const size_t F_TMP = 28100000;
  const size_t F_SRC1 = 30500000;
  const size_t F_SRC1B = 32900000;
  const size_t F_FF1 = 34100000;
  const size_t F_FF2 = 38900000;

  bf16* wkbase = (bf16*)(ws + F_WT);
  bf16* wk1 = wkbase + 0;
  bf16* wk2 = wkbase + 24576;
  bf16* wkf2 = wkbase + 466944;
  bf16* wkcf = wkbase + 540672;
  bf16* wkfh1 = wkbase + 830976;
  bf16* wl_oa = wkbase + 1125888;
  bf16* wl_val = wkbase + 1150464;
  bf16* wl_out = wkbase + 1216000;
  bf16* wl_ff1 = wkbase + 1281536;
  bf16* wl_ff2 = wkbase + 1543680;
  bf16* wk7 = wkbase + 1805824;
  bf16* f1t = (bf16*)(ws + F_F1T);
  bf16* f2t = (bf16*)(ws + F_F2T);
  bf16* qb = (bf16*)(ws + F_QB);
  bf16* cf = (bf16*)(ws + F_CF);
  bf16* col7 = (bf16*)(ws + F_COL7);
  bf16* cor1 = (bf16*)(ws + F_COR1);
  bf16* flo1 = (bf16*)(ws + F_FLO1);
  bf16* cat = (bf16*)(ws + F_CAT);
  bf16* mf = (bf16*)(ws + F_MF);
  bf16* fh1 = (bf16*)(ws + F_FH1);
  bf16* valb = (bf16*)(ws + F_VAL);
  bf16* attnb = (bf16*)(ws + F_ATTN);
  bf16* src1b = (bf16*)(ws + F_SRC1B);
  bf16* ff1b = (bf16*)(ws + F_FF1);

  // 1. weight pack
  WtSegs segs;
  const float* srcs[12] = {wc1, wc2, wf2, wcf, wfh1, w_off, w_aw, w_val, w_out, w_ff1, w_ff2, wf1};
  unsigned offs[12] = {0, 24576, 466944, 540672, 830976, 1125888, 1142272, 1150464, 1216000, 1281536, 1543680, 1805824};
  int couts[12] = {256, 192, 64, 126, 256, 64, 32, 256, 256, 1024, 256, 128};
  int cins[12] = {81, 256, 128, 256, 128, 256, 256, 256, 256, 256, 1024, 2};
  int kps[12] = {96, 256, 128, 256, 128, 256, 256, 256, 256, 256, 1024, 128};
  int ks2[12] = {1, 9, 9, 9, 9, 1, 1, 1, 1, 1, 1, 0};
  unsigned cum = 0;
  for (int i = 0; i < 12; ++i) {
    segs.src[i] = srcs[i];
    segs.dstOff[i] = offs[i];
    segs.Cout[i] = couts[i];
    segs.Cin[i] = cins[i];
    segs.KP[i] = kps[i];
    segs.KS2[i] = ks2[i];
    segs.cum[i] = cum;
    cum += (unsigned)((ks2[i] ? ks2[i] : 1) * couts[i] * kps[i]);
  }
  segs.cum[12] = cum;
  wt_all_k<<<dim3((cum + 255) / 256), 256, 0, stream>>>(segs, wkbase);

  // 2-4. prep, im2col7, copy_flow
  prep_k<<<dim3(36, 4, 8), 256, 0, stream>>>(fmap1, fmap2, ws + F_SRCT, f1t, qb, f2t);
  im2col7_k<<<dim3(4608), 256, 0, stream>>>(flow, col7);
  copy_flow_k<<<dim3(72), 256, 0, stream>>>(flow, mf);

  // 5. FUSED corr+lookup (1024-thr blocks, XCD-swizzled)
  fused_corr_k<<<dim3(2304), 1024, 0, stream>>>(f1t, f2t, flow, cf);

  auto setseg = [](GSegs& G, int i, const bf16* in, const bf16* wt, const float* bias,
                   const float* bias2, int split, float* outf, bf16* outb, int O, int KP,
                   int taps, int OStride, int OOff, int relu) {
    G.in[i] = in; G.wt[i] = wt; G.bias[i] = bias; G.bias2[i] = bias2; G.split[i] = split;
    G.outf[i] = outf; G.outb[i] = outb; G.O[i] = O; G.KP[i] = KP; G.taps[i] = taps;
    G.OStride[i] = OStride; G.OOff[i] = OOff; G.relu[i] = relu;
    G.nTn[i] = (O + 63) / 64;
  };
  auto finseg = [](GSegs& G, int n) {
    int cumb = 0;
    for (int i = 0; i < 4; ++i) {
      if (i < n) { G.blkStart[i] = cumb; cumb += G.nTn[i] * 72; }
      else G.blkStart[i] = 0x7fffffff;
    }
    G.nseg = n;
    return cumb;
  };
  const int BIG = 1 << 30;

  // 6. GROUP A: wc1, conv7-linear, off|aw, val
  GSegs GA;
  setseg(GA, 0, cf, wk1, bc1, nullptr, BIG, nullptr, cor1, 256, 96, 1, 256, 0, 1);
  setseg(GA, 1, col7, wk7, bf1, nullptr, BIG, nullptr, flo1, 128, 128, 1, 128, 0, 1);
  setseg(GA, 2, qb, wl_oa, b_off, b_aw, 64, ws + F_OA, nullptr, 96, 256, 1, 96, 0, 0);
  setseg(GA, 3, f1t, wl_val, b_val, nullptr, BIG, nullptr, valb, 256, 256, 1, 256, 0, 0);
  int nblkA = finseg(GA, 4);
  gemm_group_k<<<dim3(nblkA), 256, 0, stream>>>(GA);

  // 7. deform (bf16 val, 1024-thr blocks, XCD-swizzled)
  deform_k<<<dim3(2304), 1024, 0, stream>>>(valb, ws + F_OA, attnb);

  // 8. GROUP B: wc2, wf2, out-proj
  GSegs GB;
  setseg(GB, 0, cor1, wk2, bc2, nullptr, BIG, nullptr, cat, 192, 256, 9, 256, 0, 1);
  setseg(GB, 1, flo1, wkf2, bf2, nullptr, BIG, nullptr, cat, 64, 128, 9, 256, 192, 1);
  setseg(GB, 2, attnb, wl_out, b_out, nullptr, BIG, ws + F_TMP, nullptr, 256, 256, 1, 256, 0, 0);
  int nblkB = finseg(GB, 3);
  gemm_group_k<<<dim3(nblkB), 256, 0, stream>>>(GB);

  // 9. LN1
  ln_add_k<<<dim3(9216), 256, 0, stream>>>(ws + F_TMP, ws + F_SRCT, ln1_g, ln1_b, ws + F_SRC1, src1b);

  // 10. GROUP C: wcf, ff1
  GSegs GC;
  setseg(GC, 0, cat, wkcf, bcf, nullptr, BIG, nullptr, mf, 126, 256, 9, 128, 0, 1);
  setseg(GC, 1, src1b, wl_ff1, b_ff1, nullptr, BIG, nullptr, ff1b, 1024, 256, 1, 1024, 0, 1);
  int nblkC = finseg(GC, 2);
  gemm_group_k<<<dim3(nblkC), 256, 0, stream>>>(GC);

  // 11. GROUP D: wfh1, ff2
  GSegs GD;
  setseg(GD, 0, mf, wkfh1, bfh1, nullptr, BIG, nullptr, fh1, 256, 128, 9, 256, 0, 1);
  setseg(GD, 1, ff1b, wl_ff2, b_ff2, nullptr, BIG, ws + F_FF2, nullptr, 256, 1024, 1, 256, 0, 0);
  int nblkD = finseg(GD, 2);
  gemm_group_k<<<dim3(nblkD), 256, 0, stream>>>(GD);

  // 12-13. flow head tail + LN2
  convfh2_k<<<dim3(2304), 256, 0, stream>>>(fh1, wfh2, bfh2, out_df);
  ln_add_k<<<dim3(9216), 256, 0, stream>>>(ws + F_FF2, ws + F_SRC1, ln2_g, ln2_b, out_src, nullptr);

  (void)in_sizes; (void)n_in; (void)out_size; (void)ws_size;
}

// Round 21
// 260.394 us; speedup vs baseline: 1.0466x; 1.0466x over previous
//
#include <hip/hip_runtime.h>
#include <hip/hip_bf16.h>
#include <math.h>

#define HH 48
#define WW 48
#define HW 2304
#define BB 4
#define CC 256

typedef __hip_bfloat16 bf16;
typedef __attribute__((ext_vector_type(8))) short s8v;
typedef __attribute__((ext_vector_type(4))) float f4v;

__device__ inline float bf2f(short u) {
  unsigned v = ((unsigned)(unsigned short)u) << 16;
  return __builtin_bit_cast(float, v);
}

// ---------------- prep: z<4 -> fmap2 transpose; z>=4 -> fmap1 transpose + srcT/qb ----
__global__ __launch_bounds__(256) void prep_k(const float* __restrict__ fmap1,
                                              const float* __restrict__ fmap2,
                                              float* __restrict__ srcT,
                                              bf16* __restrict__ f1t,
                                              bf16* __restrict__ qb,
                                              bf16* __restrict__ f2t) {
  __shared__ float t[64][65];
  int z = blockIdx.z;
  int p0 = blockIdx.x * 64, c0 = blockIdx.y * 64;
  int b = z & 3;
  const float* src = (z < 4) ? fmap2 : fmap1;
  const float* inb = src + ((size_t)b * CC + c0) * HW + p0;
#pragma unroll
  for (int i = 0; i < 16; ++i) {
    int idx = threadIdx.x + i * 256;
    int c = idx >> 6, p = idx & 63;
    t[c][p] = inb[(size_t)c * HW + p];
  }
  __syncthreads();
  if (z < 4) {
    bf16* ob = f2t + ((size_t)b * HW + p0) * 256 + c0;
#pragma unroll
    for (int i = 0; i < 16; ++i) {
      int idx = threadIdx.x + i * 256;
      int p = idx >> 6, c = idx & 63;
      ob[(size_t)p * 256 + c] = (bf16)t[c][p];
    }
  } else {
    const float TWO_PI = 6.283185307179586f;
#pragma unroll
    for (int i = 0; i < 16; ++i) {
      int idx = threadIdx.x + i * 256;
      int pl = idx >> 6, cl = idx & 63;
      int c = c0 + cl;
      int p = p0 + pl;
      int y = p / WW, x = p % WW;
      float s = t[cl][pl];
      int axis = c >> 7;
      int cc = c & 127;
      int mm = cc >> 1;
      float coord = (axis ? ((float)x + 0.5f) : ((float)y + 0.5f)) * (TWO_PI / (48.f + 1e-6f));
      float tp = exp2f((float)mm * (13.287712379549449f / 64.f));
      float a = coord / tp;
      float pv = (cc & 1) ? cosf(a) : sinf(a);
      size_t o = ((size_t)b * HW + p) * 256 + c;
      srcT[o] = s;
      f1t[o] = (bf16)s;
      qb[o] = (bf16)(s + pv);
    }
  }
}

// ---------------- FUSED corr+lookup, 1 query/block, 4-wave K-split, XCD swizzle ----
__global__ __launch_bounds__(256) void fused_corr_k(const bf16* __restrict__ f1t,
                                                    const bf16* __restrict__ f2t,
                                                    const float* __restrict__ flow,
                                                    bf16* __restrict__ cf) {
  __shared__ float Dp[4][112];
  __shared__ float Ds[112];
  int blk = blockIdx.x;
  int q = (blk & 7) * 1152 + (blk >> 3);  // bijective XCD swizzle (9216 = 8*1152)
  int wave = threadIdx.x >> 6, lane = threadIdx.x & 63;
  int b = q / HW, p = q - b * HW;
  int y = p / WW, x = p - y * WW;
  float fx = flow[((size_t)b * 2 + 0) * HW + p];
  float fy = flow[((size_t)b * 2 + 1) * HW + p];
  float sx = (float)x + fx, sy = (float)y + fy;
  float fx0 = floorf(sx), fy0 = floorf(sy);
  int ix0 = (int)fx0, iy0 = (int)fy0;
  float wx = sx - fx0, wy = sy - fy0;
  int fl = lane & 15, fk8 = lane >> 4;
  const bf16* f1q = f1t + (size_t)q * 256 + wave * 64;
  s8v bf0 = *(const s8v*)(f1q + fk8 * 8);
  s8v bf1v = *(const s8v*)(f1q + 32 + fk8 * 8);
  const bf16* rowp[7];
#pragma unroll
  for (int g = 0; g < 7; ++g) {
    int w = g * 16 + fl;
    int jy = w / 10, jx = w - jy * 10;
    int ky = iy0 - 4 + jy, kx = ix0 - 4 + jx;
    bool valid = (w < 100) && ((unsigned)kx < (unsigned)WW) && ((unsigned)ky < (unsigned)HH);
    rowp[g] = valid ? (f2t + ((size_t)b * HW + ky * WW + kx) * 256 + wave * 64) : nullptr;
  }
  s8v a0[7], a1[7];
#pragma unroll
  for (int g = 0; g < 7; ++g) {
    s8v z = {0, 0, 0, 0, 0, 0, 0, 0};
    a0[g] = rowp[g] ? *(const s8v*)(rowp[g] + fk8 * 8) : z;
  }
#pragma unroll
  for (int g = 0; g < 7; ++g) {
    s8v z = {0, 0, 0, 0, 0, 0, 0, 0};
    a1[g] = rowp[g] ? *(const s8v*)(rowp[g] + 32 + fk8 * 8) : z;
  }
  f4v acc[7] = {};
#pragma unroll
  for (int g = 0; g < 7; ++g)
    acc[g] = __builtin_amdgcn_mfma_f32_16x16x32_bf16(a0[g], bf0, acc[g], 0, 0, 0);
#pragma unroll
  for (int g = 0; g < 7; ++g)
    acc[g] = __builtin_amdgcn_mfma_f32_16x16x32_bf16(a1[g], bf1v, acc[g], 0, 0, 0);
  if (fl == 0) {
#pragma unroll
    for (int g = 0; g < 7; ++g)
#pragma unroll
      for (int r = 0; r < 4; ++r)
        Dp[wave][g * 16 + fk8 * 4 + r] = acc[g][r];
  }
  __syncthreads();
  int tid = threadIdx.x;
  if (tid < 112) Ds[tid] = (Dp[0][tid] + Dp[1][tid] + Dp[2][tid] + Dp[3][tid]) * 0.0625f;
  __syncthreads();
  if (tid < 96) {
    float w00 = (1.f - wx) * (1.f - wy), w10 = wx * (1.f - wy);
    float w01 = (1.f - wx) * wy, w11 = wx * wy;
    float v = 0.f;
    if (tid < 81) {
      int jx = tid / 9, jy = tid - jx * 9;  // px offset uses t/9, py uses t%9 (RAFT quirk)
      v = w00 * Ds[jy * 10 + jx] + w10 * Ds[jy * 10 + jx + 1] +
          w01 * Ds[(jy + 1) * 10 + jx] + w11 * Ds[(jy + 1) * 10 + jx + 1];
    }
    cf[(size_t)q * 96 + tid] = (bf16)v;
  }
}

// ---------------- fused weight conversion: 12 segments (KS2==0 => conv7 repack) ----
struct WtSegs {
  const float* src[12];
  unsigned dstOff[12];
  int Cout[12], Cin[12], KP[12], KS2[12];
  unsigned cum[13];
};

__global__ __launch_bounds__(256) void wt_all_k(WtSegs s, bf16* __restrict__ base) {
  unsigned idx = blockIdx.x * 256 + threadIdx.x;
  if (idx >= s.cum[12]) return;
  int seg = 0;
#pragma unroll
  for (int i = 1; i < 12; ++i)
    if (idx >= s.cum[i]) seg = i;
  unsigned r = idx - s.cum[seg];
  int KP = s.KP[seg], Cout = s.Cout[seg], Cin = s.Cin[seg], KS2 = s.KS2[seg];
  int c = r % KP;
  int o = (r / KP) % Cout;
  int t = r / (KP * Cout);
  float v;
  if (KS2 == 0) {
    int cc = c >> 6, tt = c & 63;
    v = (tt < 49) ? s.src[seg][((size_t)o * 2 + cc) * 49 + tt] : 0.f;
  } else {
    v = (c < Cin) ? s.src[seg][((size_t)o * Cin + c) * KS2 + t] : 0.f;
  }
  base[s.dstOff[seg] + r] = (bf16)v;
}

// ---------------- im2col for 7x7 pad3 conv on flow: col7[n][128] bf16 ----
__global__ __launch_bounds__(256) void im2col7_k(const float* __restrict__ flow,
                                                 bf16* __restrict__ col7) {
  int g = blockIdx.x * 256 + threadIdx.x;
  int kp = g & 127;
  int n = g >> 7;
  int b = n / HW;
  int p = n % HW;
  int y = p / WW, x = p % WW;
  int cc = kp >> 6, tt = kp & 63;
  float v = 0.f;
  if (tt < 49) {
    int ky = tt / 7, kx = tt % 7;
    int yy = y + ky - 3, xx = x + kx - 3;
    if ((unsigned)yy < (unsigned)HH && (unsigned)xx < (unsigned)WW)
      v = flow[((size_t)b * 2 + cc) * HW + yy * WW + xx];
  }
  col7[g] = (bf16)v;
}

// ---------------- grouped GEMM: 2-deep reg prefetch + LDS dbuf (S always even) ----
struct GSegs {
  const bf16* in[4];
  const bf16* wt[4];
  const float* bias[4];
  const float* bias2[4];
  float* outf[4];
  bf16* outb[4];
  int split[4], O[4], KP[4], taps[4], OStride[4], OOff[4], relu[4], nTn[4];
  int blkStart[4];
  int nseg;
};

__global__ __launch_bounds__(256) void gemm_group_k(GSegs s) {
  int blk = blockIdx.x;
  int seg = 0;
#pragma unroll
  for (int i = 1; i < 4; ++i)
    if (i < s.nseg && blk >= s.blkStart[i]) seg = i;
  int rel = blk - s.blkStart[seg];
  int nTn = s.nTn[seg];
  int bm = rel / nTn, bn = rel % nTn;
  int m0 = bm * 128, n0 = bn * 64;
  int KP = s.KP[seg], O = s.O[seg], taps = s.taps[seg];
  const bf16* in = s.in[seg];
  const bf16* wt = s.wt[seg];

  __shared__ short As[2][128][64];
  __shared__ short Bs[2][64][64];
  int tid = threadIdx.x;
  int arl = tid >> 1, asl = (tid & 1) * 4;
  int brl = tid >> 2, bsl = (tid & 3) * 2;
  int wave = tid >> 6, lane = tid & 63;
  int wm = (wave >> 1) * 64, wn = (wave & 1) * 32;
  int fl = lane & 15, fk8 = lane >> 4;
  f4v acc[4][2] = {};
  int m = m0 + arl;
  int b = m / HW;
  int p = m - b * HW;
  int y = p / WW, x = p - y * WW;
  int wo = n0 + brl;
  bool wvalid = wo < O;
  int wo_c = wvalid ? wo : 0;

  int nc0 = (KP + 63) >> 6;
  int S = taps * nc0;  // even for all launched segments
  uint4 apA[4], bpA[2], apB[4], bpB[2];

  auto load_stage = [&](int st, uint4* ap, uint4* bp) {
    int t = st / nc0;
    int c0 = (st - t * nc0) * 64;
    int yy = y, xx = x;
    bool valid = true;
    if (taps == 9) {
      int ky = t / 3, kx = t - ky * 3;
      yy = y + ky - 1;
      xx = x + kx - 1;
      valid = ((unsigned)yy < (unsigned)HH) & ((unsigned)xx < (unsigned)WW);
    }
    const bf16* arow = in + ((size_t)b * HW + yy * WW + xx) * KP;
    const bf16* wrow = wt + ((size_t)t * O + wo_c) * KP;
#pragma unroll
    for (int qq = 0; qq < 4; ++qq) {
      int col = c0 + (asl + qq) * 8;
      uint4 v = {0u, 0u, 0u, 0u};
      if (valid && col < KP) v = *(const uint4*)(arow + col);
      ap[qq] = v;
    }
#pragma unroll
    for (int qq = 0; qq < 2; ++qq) {
      int col = c0 + (bsl + qq) * 8;
      uint4 v = {0u, 0u, 0u, 0u};
      if (wvalid && col < KP) v = *(const uint4*)(wrow + col);
      bp[qq] = v;
    }
  };
  auto write_lds = [&](int cur, const uint4* ap, const uint4* bp) {
#pragma unroll
    for (int qq = 0; qq < 4; ++qq) {
      int sr = asl + qq;
      *(uint4*)&As[cur][arl][((sr ^ (arl & 7))) * 8] = ap[qq];
    }
#pragma unroll
    for (int qq = 0; qq < 2; ++qq) {
      int sr = bsl + qq;
      *(uint4*)&Bs[cur][brl][((sr ^ (brl & 7))) * 8] = bp[qq];
    }
  };
  auto compute = [&](int cur) {
#pragma unroll
    for (int cc = 0; cc < 2; ++cc) {
      s8v af[4], bfr[2];
#pragma unroll
      for (int i = 0; i < 4; ++i) {
        int ar = wm + i * 16 + fl;
        af[i] = *(const s8v*)&As[cur][ar][(((cc * 4 + fk8) ^ (ar & 7))) * 8];
      }
#pragma unroll
      for (int j = 0; j < 2; ++j) {
        int br = wn + j * 16 + fl;
        bfr[j] = *(const s8v*)&Bs[cur][br][(((cc * 4 + fk8) ^ (br & 7))) * 8];
      }
#pragma unroll
      for (int i = 0; i < 4; ++i)
#pragma unroll
        for (int j = 0; j < 2; ++j)
          acc[i][j] = __builtin_amdgcn_mfma_f32_16x16x32_bf16(af[i], bfr[j], acc[i][j], 0, 0, 0);
    }
  };

  load_stage(0, apA, bpA);
  if (S > 1) load_stage(1, apB, bpB);
  for (int st = 0; st < S; st += 2) {
    write_lds(0, apA, bpA);
    if (st + 2 < S) load_stage(st + 2, apA, bpA);
    __syncthreads();
    compute(0);
    write_lds(1, apB, bpB);
    if (st + 3 < S) load_stage(st + 3, apB, bpB);
    __syncthreads();
    compute(1);
  }

  int OStride = s.OStride[seg], OOff = s.OOff[seg], relu = s.relu[seg], split = s.split[seg];
  const float* bias = s.bias[seg];
  const float* bias2 = s.bias2[seg];
  float* outf = s.outf[seg];
  bf16* outb = s.outb[seg];
#pragma unroll
  for (int j = 0; j < 2; ++j) {
    int o = n0 + wn + j * 16 + fl;
    if (o < O) {
      float bsv = (bias2 != nullptr && o >= split) ? bias2[o - split] : bias[o];
#pragma unroll
      for (int i = 0; i < 4; ++i)
#pragma unroll
        for (int r = 0; r < 4; ++r) {
          int mm = m0 + wm + i * 16 + fk8 * 4 + r;
          float v = acc[i][j][r] + bsv;
          if (relu) v = fmaxf(v, 0.f);
          if (outb) outb[(size_t)mm * OStride + OOff + o] = (bf16)v;
          else outf[(size_t)mm * OStride + OOff + o] = v;
        }
    }
  }
}

// ---------------- final 3x3 conv 256->2, wave-per-pixel, LDS weights ----------------
__global__ __launch_bounds__(256) void convfh2_k(const bf16* __restrict__ fh1,
                                                 const float* __restrict__ w,
                                                 const float* __restrict__ bias,
                                                 float* __restrict__ out) {
  __shared__ float wl[4608];
  int tid = threadIdx.x;
#pragma unroll
  for (int i = tid; i < 4608; i += 256) {
    int o2 = i & 1;
    int t = (i >> 1) % 9;
    int c = i / 18;
    wl[i] = w[((size_t)o2 * 256 + c) * 9 + t];
  }
  __syncthreads();
  int wave = tid >> 6, lane = tid & 63;
  int pix = blockIdx.x * 4 + wave;
  int b = pix / HW;
  int q = pix % HW;
  int y = q / WW, x = q % WW;
  int c0 = lane * 4;
  float a0 = 0.f, a1 = 0.f;
#pragma unroll
  for (int ky = 0; ky < 3; ++ky) {
    int yy = y + ky - 1;
    if ((unsigned)yy >= (unsigned)HH) continue;
#pragma unroll
    for (int kx = 0; kx < 3; ++kx) {
      int xx = x + kx - 1;
      if ((unsigned)xx >= (unsigned)WW) continue;
      int t = ky * 3 + kx;
      const bf16* row = fh1 + ((size_t)b * HW + yy * WW + xx) * 256 + c0;
      ushort4 v = *(const ushort4*)row;
      unsigned short vv[4] = {v.x, v.y, v.z, v.w};
#pragma unroll
      for (int j = 0; j < 4; ++j) {
        float fv = bf2f((short)vv[j]);
        float2 wp = *(const float2*)&wl[((c0 + j) * 9 + t) * 2];
        a0 += fv * wp.x;
        a1 += fv * wp.y;
      }
    }
  }
#pragma unroll
  for (int offl = 32; offl > 0; offl >>= 1) {
    a0 += __shfl_xor(a0, offl);
    a1 += __shfl_xor(a1, offl);
  }
  if (lane == 0) {
    out[(size_t)b * 2 * HW + q] = a0 + bias[0];
    out[((size_t)b * 2 + 1) * HW + q] = a1 + bias[1];
  }
}

// ---------------- copy flow into mf cols 126,127 ----------------
__global__ void copy_flow_k(const float* __restrict__ flow, bf16* __restrict__ mf) {
  int g = blockIdx.x * 256 + threadIdx.x;
  int p = g % HW;
  int c = (g / HW) % 2;
  int b = g / (2 * HW);
  mf[((size_t)b * HW + p) * 128 + 126 + c] = (bf16)flow[g];
}

// ---------------- deformable sampling, XCD-swizzled blocks; val bf16; oa=[n][96] ----
__global__ __launch_bounds__(256) void deform_k(const bf16* __restrict__ val,
                                                const float* __restrict__ oa,
                                                bf16* __restrict__ attn) {
  int blk = blockIdx.x;
  int n = (blk & 7) * 1152 + (blk >> 3);  // bijective XCD swizzle (block <-> one query n)
  int tid = threadIdx.x;
  int d = tid & 31;
  int h = (tid >> 5) & 7;
  int b = n / HW;
  int p = n % HW;
  int y = p / WW, x = p % WW;
  const float* ap = oa + (size_t)n * 96 + 64 + h * 4;
  float l0 = ap[0], l1 = ap[1], l2 = ap[2], l3 = ap[3];
  float mx = fmaxf(fmaxf(l0, l1), fmaxf(l2, l3));
  float e0 = expf(l0 - mx), e1 = expf(l1 - mx), e2 = expf(l2 - mx), e3 = expf(l3 - mx);
  float inv = 1.f / (e0 + e1 + e2 + e3);
  float wts[4] = {e0 * inv, e1 * inv, e2 * inv, e3 * inv};
  const float* offp = oa + (size_t)n * 96 + h * 8;
  const bf16* vb = val + (size_t)b * HW * 256 + h * 32 + d;
  float acc = 0.f;
#pragma unroll
  for (int pt = 0; pt < 4; ++pt) {
    float ox = offp[pt * 2 + 0];
    float oy = offp[pt * 2 + 1];
    float w = wts[pt];
    float px = (float)x + ox, py = (float)y + oy;
    float x0f = floorf(px), y0f = floorf(py);
    int x0 = (int)x0f, y0 = (int)y0f;
    float wx = px - x0f, wy = py - y0f;
    float s = 0.f;
    if ((unsigned)x0 < WW && (unsigned)y0 < HH)
      s += (float)vb[(size_t)(y0 * WW + x0) * 256] * (1.f - wx) * (1.f - wy);
    if ((unsigned)(x0 + 1) < WW && (unsigned)y0 < HH)
      s += (float)vb[(size_t)(y0 * WW + x0 + 1) * 256] * wx * (1.f - wy);
    if ((unsigned)x0 < WW && (unsigned)(y0 + 1) < HH)
      s += (float)vb[(size_t)((y0 + 1) * WW + x0) * 256] * (1.f - wx) * wy;
    if ((unsigned)(x0 + 1) < WW && (unsigned)(y0 + 1) < HH)
      s += (float)vb[(size_t)((y0 + 1) * WW + x0 + 1) * 256] * wx * wy;
    acc += w * s;
  }
  attn[(size_t)n * 256 + h * 32 + d] = (bf16)acc;
}

// ---------------- fused residual add + LayerNorm over 256 (optional bf16 copy) ----
__global__ __launch_bounds__(256) void ln_add_k(const float* __restrict__ A,
                                                const float* __restrict__ Bv,
                                                const float* __restrict__ g,
                                                const float* __restrict__ be,
                                                float* __restrict__ out,
                                                bf16* __restrict__ outb) {
  int n = blockIdx.x;
  int c = threadIdx.x;
  float v = A[(size_t)n * 256 + c] + Bv[(size_t)n * 256 + c];
  float s1 = v, s2 = v * v;
#pragma unroll
  for (int o = 32; o > 0; o >>= 1) {
    s1 += __shfl_down(s1, o);
    s2 += __shfl_down(s2, o);
  }
  __shared__ float r1[4], r2[4], mv[2];
  int wid = c >> 6, lane = c & 63;
  if (lane == 0) {
    r1[wid] = s1;
    r2[wid] = s2;
  }
  __syncthreads();
  if (c == 0) {
    float a = r1[0] + r1[1] + r1[2] + r1[3];
    float q2 = r2[0] + r2[1] + r2[2] + r2[3];
    float mean = a * (1.f / 256.f);
    mv[0] = mean;
    mv[1] = q2 * (1.f / 256.f) - mean * mean;
  }
  __syncthreads();
  float mean = mv[0], var = mv[1];
  float r = (v - mean) * rsqrtf(var + 1e-5f) * g[c] + be[c];
  out[(size_t)n * 256 + c] = r;
  if (outb) outb[(size_t)n * 256 + c] = (bf16)r;
}

extern "C" void kernel_launch(void* const* d_in, const int* in_sizes, int n_in,
                              void* d_out, int out_size, void* d_ws, size_t ws_size,
                              hipStream_t stream) {
  const float* fmap1 = (const float*)d_in[0];
  const float* fmap2 = (const float*)d_in[1];
  const float* flow = (const float*)d_in[2];
  const float* wc1 = (const float*)d_in[3];
  const float* bc1 = (const float*)d_in[4];
  const float* wc2 = (const float*)d_in[5];
  const float* bc2 = (const float*)d_in[6];
  const float* wf1 = (const float*)d_in[7];
  const float* bf1 = (const float*)d_in[8];
  const float* wf2 = (const float*)d_in[9];
  const float* bf2 = (const float*)d_in[10];
  const float* wcf = (const float*)d_in[11];
  const float* bcf = (const float*)d_in[12];
  const float* wfh1 = (const float*)d_in[13];
  const float* bfh1 = (const float*)d_in[14];
  const float* wfh2 = (const float*)d_in[15];
  const float* bfh2 = (const float*)d_in[16];
  const float* w_off = (const float*)d_in[17];
  const float* b_off = (const float*)d_in[18];
  const float* w_aw = (const float*)d_in[19];
  const float* b_aw = (const float*)d_in[20];
  const float* w_val = (const float*)d_in[21];
  const float* b_val = (const float*)d_in[22];
  const float* w_out = (const float*)d_in[23];
  const float* b_out = (const float*)d_in[24];
  const float* ln1_g = (const float*)d_in[25];
  const float* ln1_b = (const float*)d_in[26];
  const float* w_ff1 = (const float*)d_in[27];
  const float* b_ff1 = (const float*)d_in[28];
  const float* w_ff2 = (const float*)d_in[29];
  const float* b_ff2 = (const float*)d_in[30];
  const float* ln2_g = (const float*)d_in[31];
  const float* ln2_b = (const float*)d_in[32];

  float* ws = (float*)d_ws;
  float* out_src = (float*)d_out;
  float* out_df = out_src + (size_t)BB * HW * CC;

  // ---- workspace layout (float offsets) ----
  const size_t F_WT = 0;
  const size_t F_F1T = 11700000;
  const size_t F_F2T = 12900000;
  const size_t F_QB = 14100000;
  const size_t F_SRCT = 15300000;
  const size_t F_CF = 17700000;
  const size_t F_COL7 = 18200000;
  const size_t F_COR1 = 18800000;
  const size_t F_FLO1 = 20000000;
  const size_t F_CAT = 20600000;
  const size_t F_MF = 21800000;
  const size_t F_FH1 = 22400000;
  const size_t F_OA = 23600000;
  const size_t F_VAL = 24500000;   // bf16 [n][256]
  const size_t F_ATTN = 26900000;
  const size_t F_TMP = 28100000;
  const size_t F_SRC1 = 30500000;
  const size_t F_SRC1B = 32900000;
  const size_t F_FF1 = 34100000;
  const size_t F_FF2 = 38900000;

  bf16* wkbase = (bf16*)(ws + F_WT);
  bf16* wk1 = wkbase + 0;
  bf16* wk2 = wkbase + 24576;
  bf16* wkf2 = wkbase + 466944;
  bf16* wkcf = wkbase + 540672;
  bf16* wkfh1 = wkbase + 830976;
  bf16* wl_oa = wkbase + 1125888;
  bf16* wl_val = wkbase + 1150464;
  bf16* wl_out = wkbase + 1216000;
  bf16* wl_ff1 = wkbase + 1281536;
  bf16* wl_ff2 = wkbase + 1543680;
  bf16* wk7 = wkbase + 1805824;
  bf16* f1t = (bf16*)(ws + F_F1T);
  bf16* f2t = (bf16*)(ws + F_F2T);
  bf16* qb = (bf16*)(ws + F_QB);
  bf16* cf = (bf16*)(ws + F_CF);
  bf16* col7 = (bf16*)(ws + F_COL7);
  bf16* cor1 = (bf16*)(ws + F_COR1);
  bf16* flo1 = (bf16*)(ws + F_FLO1);
  bf16* cat = (bf16*)(ws + F_CAT);
  bf16* mf = (bf16*)(ws + F_MF);
  bf16* fh1 = (bf16*)(ws + F_FH1);
  bf16* valb = (bf16*)(ws + F_VAL);
  bf16* attnb = (bf16*)(ws + F_ATTN);
  bf16* src1b = (bf16*)(ws + F_SRC1B);
  bf16* ff1b = (bf16*)(ws + F_FF1);

  // 1. weight pack
  WtSegs segs;
  const float* srcs[12] = {wc1, wc2, wf2, wcf, wfh1, w_off, w_aw, w_val, w_out, w_ff1, w_ff2, wf1};
  unsigned offs[12] = {0, 24576, 466944, 540672, 830976, 1125888, 1142272, 1150464, 1216000, 1281536, 1543680, 1805824};
  int couts[12] = {256, 192, 64, 126, 256, 64, 32, 256, 256, 1024, 256, 128};
  int cins[12] = {81, 256, 128, 256, 128, 256, 256, 256, 256, 256, 1024, 2};
  int kps[12] = {96, 256, 128, 256, 128, 256, 256, 256, 256, 256, 1024, 128};
  int ks2[12] = {1, 9, 9, 9, 9, 1, 1, 1, 1, 1, 1, 0};
  unsigned cum = 0;
  for (int i = 0; i < 12; ++i) {
    segs.src[i] = srcs[i];
    segs.dstOff[i] = offs[i];
    segs.Cout[i] = couts[i];
    segs.Cin[i] = cins[i];
    segs.KP[i] = kps[i];
    segs.KS2[i] = ks2[i];
    segs.cum[i] = cum;
    cum += (unsigned)((ks2[i] ? ks2[i] : 1) * couts[i] * kps[i]);
  }
  segs.cum[12] = cum;
  wt_all_k<<<dim3((cum + 255) / 256), 256, 0, stream>>>(segs, wkbase);

  // 2-4. prep, im2col7, copy_flow
  prep_k<<<dim3(36, 4, 8), 256, 0, stream>>>(fmap1, fmap2, ws + F_SRCT, f1t, qb, f2t);
  im2col7_k<<<dim3(4608), 256, 0, stream>>>(flow, col7);
  copy_flow_k<<<dim3(72), 256, 0, stream>>>(flow, mf);

  // 5. FUSED corr+lookup (XCD-swizzled)
  fused_corr_k<<<dim3(9216), 256, 0, stream>>>(f1t, f2t, flow, cf);

  auto setseg = [](GSegs& G, int i, const bf16* in, const bf16* wt, const float* bias,
                   const float* bias2, int split, float* outf, bf16* outb, int O, int KP,
                   int taps, int OStride, int OOff, int relu) {
    G.in[i] = in; G.wt[i] = wt; G.bias[i] = bias; G.bias2[i] = bias2; G.split[i] = split;
    G.outf[i] = outf; G.outb[i] = outb; G.O[i] = O; G.KP[i] = KP; G.taps[i] = taps;
    G.OStride[i] = OStride; G.OOff[i] = OOff; G.relu[i] = relu;
    G.nTn[i] = (O + 63) / 64;
  };
  auto finseg = [](GSegs& G, int n) {
    int cumb = 0;
    for (int i = 0; i < 4; ++i) {
      if (i < n) { G.blkStart[i] = cumb; cumb += G.nTn[i] * 72; }
      else G.blkStart[i] = 0x7fffffff;
    }
    G.nseg = n;
    return cumb;
  };
  const int BIG = 1 << 30;

  // 6. GROUP A: wc1, conv7-linear, off|aw, val
  GSegs GA;
  setseg(GA, 0, cf, wk1, bc1, nullptr, BIG, nullptr, cor1, 256, 96, 1, 256, 0, 1);
  setseg(GA, 1, col7, wk7, bf1, nullptr, BIG, nullptr, flo1, 128, 128, 1, 128, 0, 1);
  setseg(GA, 2, qb, wl_oa, b_off, b_aw, 64, ws + F_OA, nullptr, 96, 256, 1, 96, 0, 0);
  setseg(GA, 3, f1t, wl_val, b_val, nullptr, BIG, nullptr, valb, 256, 256, 1, 256, 0, 0);
  int nblkA = finseg(GA, 4);
  gemm_group_k<<<dim3(nblkA), 256, 0, stream>>>(GA);

  // 7. deform (bf16 val, XCD-swizzled)
  deform_k<<<dim3(9216), 256, 0, stream>>>(valb, ws + F_OA, attnb);

  // 8. GROUP B: wc2, wf2, out-proj
  GSegs GB;
  setseg(GB, 0, cor1, wk2, bc2, nullptr, BIG, nullptr, cat, 192, 256, 9, 256, 0, 1);
  setseg(GB, 1, flo1, wkf2, bf2, nullptr, BIG, nullptr, cat, 64, 128, 9, 256, 192, 1);
  setseg(GB, 2, attnb, wl_out, b_out, nullptr, BIG, ws + F_TMP, nullptr, 256, 256, 1, 256, 0, 0);
  int nblkB = finseg(GB, 3);
  gemm_group_k<<<dim3(nblkB), 256, 0, stream>>>(GB);

  // 9. LN1
  ln_add_k<<<dim3(9216), 256, 0, stream>>>(ws + F_TMP, ws + F_SRCT, ln1_g, ln1_b, ws + F_SRC1, src1b);

  // 10. GROUP C: wcf, ff1
  GSegs GC;
  setseg(GC, 0, cat, wkcf, bcf, nullptr, BIG, nullptr, mf, 126, 256, 9, 128, 0, 1);
  setseg(GC, 1, src1b, wl_ff1, b_ff1, nullptr, BIG, nullptr, ff1b, 1024, 256, 1, 1024, 0, 1);
  int nblkC = finseg(GC, 2);
  gemm_group_k<<<dim3(nblkC), 256, 0, stream>>>(GC);

  // 11. GROUP D: wfh1, ff2
  GSegs GD;
  setseg(GD, 0, mf, wkfh1, bfh1, nullptr, BIG, nullptr, fh1, 256, 128, 9, 256, 0, 1);
  setseg(GD, 1, ff1b, wl_ff2, b_ff2, nullptr, BIG, ws + F_FF2, nullptr, 256, 1024, 1, 256, 0, 0);
  int nblkD = finseg(GD, 2);
  gemm_group_k<<<dim3(nblkD), 256, 0, stream>>>(GD);

  // 12-13. flow head tail + LN2
  convfh2_k<<<dim3(2304), 256, 0, stream>>>(fh1, wfh2, bfh2, out_df);
  ln_add_k<<<dim3(9216), 256, 0, stream>>>(ws + F_FF2, ws + F_SRC1, ln2_g, ln2_b, out_src, nullptr);

  (void)in_sizes; (void)n_in; (void)out_size; (void)ws_size;
}